// Round 11
// baseline (57.654 us; speedup 1.0000x reference)
//
#include <hip/hip_runtime.h>

typedef unsigned int u32;
typedef unsigned short u16;
typedef _Float16 f16;
typedef __attribute__((ext_vector_type(2))) _Float16 f16x2;
typedef __attribute__((ext_vector_type(4))) _Float16 f16x4;
typedef __attribute__((ext_vector_type(8))) _Float16 f16x8;
typedef __attribute__((ext_vector_type(4))) float f32x4;
typedef __attribute__((ext_vector_type(4))) u32 u32x4;

#if __has_builtin(__builtin_amdgcn_mfma_f32_16x16x16f16)
#define USE_K16 1
#else
#define USE_K16 0
#endif

__device__ __forceinline__ float bf16_lo(u32 u) { u32 x = u << 16; return __builtin_bit_cast(float, x); }
__device__ __forceinline__ float bf16_hi(u32 u) { u32 x = u & 0xffff0000u; return __builtin_bit_cast(float, x); }
__device__ __forceinline__ float bf16f(u16 v) { u32 x = ((u32)v) << 16; return __builtin_bit_cast(float, x); }
__device__ __forceinline__ u16 f2bf(float f) {  // round-to-nearest-even (proven)
    u32 x = __builtin_bit_cast(u32, f);
    return (u16)((x + 0x7fffu + ((x >> 16) & 1u)) >> 16);
}

// ---------------------------------------------------------------------------
// k_prep: featp[row][col] = bf16(feat[row][col]) for col<25, else 0. (VERBATIM r10)
// ---------------------------------------------------------------------------
__global__ __launch_bounds__(256) void k_prep(const float* __restrict__ feat,
                                              u16* __restrict__ featp, int N) {
    int t = blockIdx.x * 256 + threadIdx.x;
    int row = t >> 5, col = t & 31;
    if (row >= N) return;
    featp[(size_t)row * 32 + col] = (col < 25) ? f2bf(feat[(size_t)row * 25 + col]) : (u16)0;
}

// ---------------------------------------------------------------------------
// M[row][col]: folded layer-1 matrix, K=128 row map (VERBATIM r10).
// ---------------------------------------------------------------------------
__device__ float m_val(int row, int col, const float* __restrict__ W,
                       const float* __restrict__ a1) {
    if (row >= 96) {
        int k = row - 96;
        return (k < 25 && col >= 64) ? W[k * 64 + (col - 64)] : 0.f;
    }
    int seg = row >> 5;
    int k = row & 31;
    if (k >= 25) return 0.f;
    int cc = (col < 64) ? col : col - 64;
    int arow = (col < 64) ? cc : 64 + cc;
    float e0 = __expf(a1[arow * 3 + 0]);
    float e1 = __expf(a1[arow * 3 + 1]);
    float e2 = __expf(a1[arow * 3 + 2]);
    float wt = ((seg == 0) ? e0 : (seg == 1) ? e1 : e2) / (e0 + e1 + e2);
    float v = W[k * 64 + cc] * wt * (1.f / 32.f);
    return (col < 64) ? v : -v;
}

// k_prepM: Bpack = M pre-packed into MFMA B-fragment order (VERBATIM r10).
__global__ __launch_bounds__(256) void k_prepM(const float* __restrict__ W,
                                               const float* __restrict__ a1,
                                               f16* __restrict__ Bpack) {
    int idx = blockIdx.x * 256 + threadIdx.x;   // 64 blocks -> 16384
#if USE_K16
    int j = idx & 3, l = (idx >> 2) & 63, ks = (idx >> 8) & 7, ct = idx >> 11;
    int row = ks * 16 + ((l >> 4) << 2) + j;
#else
    int j = idx & 7, l = (idx >> 3) & 63, ks = (idx >> 9) & 3, ct = idx >> 11;
    int row = ks * 32 + ((l >> 4) << 3) + j;
#endif
    int col = ct * 16 + (l & 15);
    Bpack[idx] = (f16)m_val(row, col, W, a1);
}

// ---------------------------------------------------------------------------
// k_layer1f v3: FUSED gather + MFMA, max memory-level parallelism.
//  Stage: 16x96 adj indices into LDS (r10-proven staging).
//  Gather (r10 lane roles: q=l>>4 sub-offset, m=(l>>2)&3 node, e=l&3 16B seg):
//    ALL 24 row-loads (3 rel x 8 steps, 16 distinct 64B rows per instr)
//    issued into vb[24] BEFORE any accumulation -> 24 outstanding per wave.
//    Reduce over q with PROVEN shfl_xor 16/32; q==0 lanes write x cols.
//  A-fragment self rows (k=96..127) read DIRECTLY from feat (no LDS staging).
//  MFMA: r10-verbatim math; x cols 0..95 = 3x32 neighbor sums.
// ---------------------------------------------------------------------------
__global__ __launch_bounds__(256) void k_layer1f(const float* __restrict__ feat,
                                                 const u16* __restrict__ featp,
                                                 const int* __restrict__ adj,
                                                 const f16* __restrict__ Bpack,
                                                 u16* __restrict__ w1, int N) {
    __shared__ f16 x[16][104];       // cols 0..95 used; stride 104 (16B-aligned)
    __shared__ int s_idx[16][104];   // 96 used; stride 104 spreads banks
    int tid = threadIdx.x;
    int i0 = blockIdx.x * 16;

    {   // stage indices: thread t -> node t>>4, lane16 t&15; 6 coalesced loads
        int node = tid >> 4, l16 = tid & 15;
        int nsafe = (i0 + node < N) ? (i0 + node) : 0;
#pragma unroll
        for (int j = 0; j < 6; ++j) {
            int jj = l16 + j * 16;        // 0..95
            int rr = jj >> 5, kk = jj & 31;
            s_idx[node][jj] = __builtin_nontemporal_load(adj + ((size_t)rr * N + nsafe) * 32 + kk);
        }
    }
    __syncthreads();

    int w = tid >> 6;
    int l = tid & 63;
    int q = l >> 4;        // neighbor sub-offset 0..3
    int m = (l >> 2) & 3;  // node within wave
    int e = l & 3;         // 16B segment of the 64B row
    int nodeLocal = w * 4 + m;
    const u32* fp = (const u32*)featp;   // 16 u32 per 64B row

    // ---- issue ALL 24 gather loads up front (max outstanding misses) ----
    u32x4 vb[24];
#pragma unroll
    for (int r = 0; r < 3; ++r)
#pragma unroll
        for (int kq = 0; kq < 8; ++kq) {
            int nb = s_idx[nodeLocal][r * 32 + kq * 4 + q];
            vb[r * 8 + kq] = *(const u32x4*)(fp + (size_t)nb * 16 + e * 4);
        }

#pragma unroll
    for (int r = 0; r < 3; ++r) {
        float acc[8];
#pragma unroll
        for (int j = 0; j < 8; ++j) acc[j] = 0.f;
#pragma unroll
        for (int kq = 0; kq < 8; ++kq) {
            u32x4 v = vb[r * 8 + kq];
            acc[0] += bf16_lo(v[0]); acc[1] += bf16_hi(v[0]);
            acc[2] += bf16_lo(v[1]); acc[3] += bf16_hi(v[1]);
            acc[4] += bf16_lo(v[2]); acc[5] += bf16_hi(v[2]);
            acc[6] += bf16_lo(v[3]); acc[7] += bf16_hi(v[3]);
        }
#pragma unroll
        for (int j = 0; j < 8; ++j) {   // reduce over q: PROVEN masks 16,32 only
            acc[j] += __shfl_xor(acc[j], 16, 64);
            acc[j] += __shfl_xor(acc[j], 32, 64);
        }
        if (q == 0) {   // 16 lanes write 16B each: cols r*32 + e*8 .. +7
            f16x2 p0, p1, p2, p3;
            p0[0] = (f16)acc[0]; p0[1] = (f16)acc[1];
            p1[0] = (f16)acc[2]; p1[1] = (f16)acc[3];
            p2[0] = (f16)acc[4]; p2[1] = (f16)acc[5];
            p3[0] = (f16)acc[6]; p3[1] = (f16)acc[7];
            u32x4 ov;
            ov[0] = __builtin_bit_cast(u32, p0);
            ov[1] = __builtin_bit_cast(u32, p1);
            ov[2] = __builtin_bit_cast(u32, p2);
            ov[3] = __builtin_bit_cast(u32, p3);
            *(u32x4*)&x[nodeLocal][r * 32 + e * 8] = ov;
        }
    }
    __syncthreads();

    // ---- MFMA phase (r10-proven math; self rows direct from feat) ----
    int nodeA = l & 15;
    int nsA = (i0 + nodeA < N) ? (i0 + nodeA) : 0;
    const float* fr = feat + (size_t)nsA * 25;
#if USE_K16
    f16x4 a[8];
    {
        const f16* xrow = &x[nodeA][(l >> 4) << 2];
#pragma unroll
        for (int ks = 0; ks < 6; ++ks) a[ks] = *(const f16x4*)(xrow + ks * 16);
#pragma unroll
        for (int ks = 6; ks < 8; ++ks)
#pragma unroll
            for (int j = 0; j < 4; ++j) {
                int k = (ks - 6) * 16 + ((l >> 4) << 2) + j;   // self col 0..31
                a[ks][j] = (k < 25) ? (f16)fr[k] : (f16)0.f;
            }
    }
#pragma unroll
    for (int ctt = 0; ctt < 2; ++ctt) {
        int ct = w * 2 + ctt;
        f32x4 d = {0.f, 0.f, 0.f, 0.f};
        const f16* bp = Bpack + ((size_t)(ct * 8) * 64 + l) * 4;
#pragma unroll
        for (int ks = 0; ks < 8; ++ks) {
            f16x4 b = *(const f16x4*)(bp + ks * 256);
            d = __builtin_amdgcn_mfma_f32_16x16x16f16(a[ks], b, d, 0, 0, 0);
        }
#pragma unroll
        for (int reg = 0; reg < 4; ++reg) {
            int n2 = i0 + ((l >> 4) << 2) + reg;
            if (n2 < N) w1[(size_t)n2 * 128 + ct * 16 + (l & 15)] = f2bf(d[reg]);
        }
    }
#else
    f16x8 a[4];
    {
        const f16* xrow = &x[nodeA][(l >> 4) << 3];
#pragma unroll
        for (int ks = 0; ks < 3; ++ks) a[ks] = *(const f16x8*)(xrow + ks * 32);
#pragma unroll
        for (int j = 0; j < 8; ++j) {
            int k = ((l >> 4) << 3) + j;                        // self col 0..31
            a[3][j] = (k < 25) ? (f16)fr[k] : (f16)0.f;
        }
    }
#pragma unroll
    for (int ctt = 0; ctt < 2; ++ctt) {
        int ct = w * 2 + ctt;
        f32x4 d = {0.f, 0.f, 0.f, 0.f};
        const f16* bp = Bpack + ((size_t)(ct * 4) * 64 + l) * 8;
#pragma unroll
        for (int ks = 0; ks < 4; ++ks) {
            f16x8 b = *(const f16x8*)(bp + ks * 512);
            d = __builtin_amdgcn_mfma_f32_16x16x32_f16(a[ks], b, d, 0, 0, 0);
        }
#pragma unroll
        for (int reg = 0; reg < 4; ++reg) {
            int n2 = i0 + ((l >> 4) << 2) + reg;
            if (n2 < N) w1[(size_t)n2 * 128 + ct * 16 + (l & 15)] = f2bf(d[reg]);
        }
    }
#endif
}

// ---------------------------------------------------------------------------
// k_layer2: round-10 VERBATIM (passed).
// ---------------------------------------------------------------------------
__global__ __launch_bounds__(128) void k_layer2(const float* __restrict__ feat,
                                                const float* __restrict__ Wmlp,
                                                const u16* __restrict__ w1h,
                                                const float* __restrict__ alpha2,
                                                const float* __restrict__ lw,
                                                const float* __restrict__ prior,
                                                const int* __restrict__ adj,
                                                const int* __restrict__ nodes,
                                                float* __restrict__ out, int N) {
    __shared__ int s_idx[96];
    __shared__ float s_red[4];
    int b = blockIdx.x;
    int i = nodes[b];
    int t = threadIdx.x;

    if (t < 96) {
        int r = t >> 5, k = t & 31;
        s_idx[t] = adj[((size_t)r * N + i) * 32 + k];
    }
    __syncthreads();

    float mean[3];
#pragma unroll
    for (int r = 0; r < 3; ++r) {
        float acc = 0.f;
#pragma unroll
        for (int k = 0; k < 32; ++k)
            acc += bf16f(w1h[(size_t)s_idx[r * 32 + k] * 128 + t]);  // coalesced
        mean[r] = acc * (1.f / 32.f);
    }

    float et[3], eb[3], st = 0.f, sb = 0.f;
#pragma unroll
    for (int r = 0; r < 3; ++r) {
        et[r] = __expf(alpha2[t * 3 + r]);         st += et[r];
        eb[r] = __expf(alpha2[(128 + t) * 3 + r]); sb += eb[r];
    }
    float t2 = 0.f, wb = 0.f;
#pragma unroll
    for (int r = 0; r < 3; ++r) { t2 += et[r] * mean[r]; wb += eb[r] * mean[r]; }
    t2 /= st;
    wb /= sb;

    float t1 = bf16f(w1h[(size_t)i * 128 + t]);
    float t3 = t1 - wb;

    float p0 = t1 * lw[(64 + t) * 2 + 0] + t2 * lw[(192 + t) * 2 + 0] + t3 * lw[(320 + t) * 2 + 0];
    float p1 = t1 * lw[(64 + t) * 2 + 1] + t2 * lw[(192 + t) * 2 + 1] + t3 * lw[(320 + t) * 2 + 1];
    if (t < 64) {
        float t0 = 0.f;
#pragma unroll
        for (int k = 0; k < 25; ++k) t0 += feat[(size_t)i * 25 + k] * Wmlp[k * 64 + t];
        p0 += t0 * lw[t * 2 + 0];
        p1 += t0 * lw[t * 2 + 1];
    }

#pragma unroll
    for (int off = 32; off > 0; off >>= 1) {
        p0 += __shfl_down(p0, off, 64);
        p1 += __shfl_down(p1, off, 64);
    }
    int wv = t >> 6, lane = t & 63;
    if (lane == 0) { s_red[wv * 2 + 0] = p0; s_red[wv * 2 + 1] = p1; }
    __syncthreads();
    if (t == 0) {
        out[b * 2 + 0] = s_red[0] + s_red[2] + __logf(prior[0]);
        out[b * 2 + 1] = s_red[1] + s_red[3] + __logf(prior[1]);
    }
}

extern "C" void kernel_launch(void* const* d_in, const int* in_sizes, int n_in,
                              void* d_out, int out_size, void* d_ws, size_t ws_size,
                              hipStream_t stream) {
    const float* feat   = (const float*)d_in[0];  // [N,25]
    const float* Wmlp   = (const float*)d_in[1];  // [25,64]
    const float* alpha1 = (const float*)d_in[2];  // [128,3]
    const float* alpha2 = (const float*)d_in[3];  // [256,3]
    const float* lw     = (const float*)d_in[4];  // [448,2]
    const float* prior  = (const float*)d_in[5];  // [2]
    const int*   adj    = (const int*)d_in[6];    // [3,N,32]
    const int*   nodes  = (const int*)d_in[7];    // [B]
    float* out = (float*)d_out;

    int N = in_sizes[0] / 25;   // 50000
    int B = in_sizes[7];        // 1024

    // ws: featp [N][32] u16 (3.2MB) | w1 [N][128] u16 (12.8MB) | Bpack 32KB
    // total ~16.03MB (< 28.8MB proven-safe). NO aliasing.
    char* base = (char*)d_ws;
    u16* featp = (u16*)base;
    u16* w1    = (u16*)(base + (size_t)N * 32 * 2);
    f16* Bpack = (f16*)(base + (size_t)N * 32 * 2 + (size_t)N * 128 * 2);

    k_prep   <<<(N * 32 + 255) / 256, 256, 0, stream>>>(feat, featp, N);
    k_prepM  <<<64,                   256, 0, stream>>>(Wmlp, alpha1, Bpack);
    k_layer1f<<<(N + 15) / 16,        256, 0, stream>>>(feat, featp, adj, Bpack, w1, N);
    k_layer2 <<<B,                    128, 0, stream>>>(feat, Wmlp, w1, alpha2, lw, prior, adj, nodes, out, N);
}

// Round 12
// 56.883 us; speedup vs baseline: 1.0135x; 1.0135x over previous
//
#include <hip/hip_runtime.h>

typedef unsigned int u32;
typedef unsigned short u16;
typedef _Float16 f16;
typedef __attribute__((ext_vector_type(2))) _Float16 f16x2;
typedef __attribute__((ext_vector_type(4))) _Float16 f16x4;
typedef __attribute__((ext_vector_type(8))) _Float16 f16x8;
typedef __attribute__((ext_vector_type(4))) float f32x4;
typedef __attribute__((ext_vector_type(4))) u32 u32x4;

#if __has_builtin(__builtin_amdgcn_mfma_f32_16x16x16f16)
#define USE_K16 1
#else
#define USE_K16 0
#endif

__device__ __forceinline__ float bf16_lo(u32 u) { u32 x = u << 16; return __builtin_bit_cast(float, x); }
__device__ __forceinline__ float bf16_hi(u32 u) { u32 x = u & 0xffff0000u; return __builtin_bit_cast(float, x); }
__device__ __forceinline__ float bf16f(u16 v) { u32 x = ((u32)v) << 16; return __builtin_bit_cast(float, x); }
__device__ __forceinline__ u16 f2bf(float f) {  // round-to-nearest-even (proven)
    u32 x = __builtin_bit_cast(u32, f);
    return (u16)((x + 0x7fffu + ((x >> 16) & 1u)) >> 16);
}

// ---------------------------------------------------------------------------
// k_prep: featp[row][col] = bf16(feat[row][col]) for col<25, else 0. (VERBATIM r11)
// ---------------------------------------------------------------------------
__global__ __launch_bounds__(256) void k_prep(const float* __restrict__ feat,
                                              u16* __restrict__ featp, int N) {
    int t = blockIdx.x * 256 + threadIdx.x;
    int row = t >> 5, col = t & 31;
    if (row >= N) return;
    featp[(size_t)row * 32 + col] = (col < 25) ? f2bf(feat[(size_t)row * 25 + col]) : (u16)0;
}

// ---------------------------------------------------------------------------
// M[row][col]: folded layer-1 matrix, K=128 row map (VERBATIM r11).
// ---------------------------------------------------------------------------
__device__ float m_val(int row, int col, const float* __restrict__ W,
                       const float* __restrict__ a1) {
    if (row >= 96) {
        int k = row - 96;
        return (k < 25 && col >= 64) ? W[k * 64 + (col - 64)] : 0.f;
    }
    int seg = row >> 5;
    int k = row & 31;
    if (k >= 25) return 0.f;
    int cc = (col < 64) ? col : col - 64;
    int arow = (col < 64) ? cc : 64 + cc;
    float e0 = __expf(a1[arow * 3 + 0]);
    float e1 = __expf(a1[arow * 3 + 1]);
    float e2 = __expf(a1[arow * 3 + 2]);
    float wt = ((seg == 0) ? e0 : (seg == 1) ? e1 : e2) / (e0 + e1 + e2);
    float v = W[k * 64 + cc] * wt * (1.f / 32.f);
    return (col < 64) ? v : -v;
}

// k_prepM: Bpack = M pre-packed into MFMA B-fragment order (VERBATIM r11).
__global__ __launch_bounds__(256) void k_prepM(const float* __restrict__ W,
                                               const float* __restrict__ a1,
                                               f16* __restrict__ Bpack) {
    int idx = blockIdx.x * 256 + threadIdx.x;   // 64 blocks -> 16384
#if USE_K16
    int j = idx & 3, l = (idx >> 2) & 63, ks = (idx >> 8) & 7, ct = idx >> 11;
    int row = ks * 16 + ((l >> 4) << 2) + j;
#else
    int j = idx & 7, l = (idx >> 3) & 63, ks = (idx >> 9) & 3, ct = idx >> 11;
    int row = ks * 32 + ((l >> 4) << 3) + j;
#endif
    int col = ct * 16 + (l & 15);
    Bpack[idx] = (f16)m_val(row, col, W, a1);
}

// ---------------------------------------------------------------------------
// k_layer1f v4: FUSED gather + MFMA.
//  Changes vs r11 (both scheduling/layout only, semantics identical):
//   1. s_idx stride 104 -> 100 ints: read bank = (4m + q + const) % 32 ->
//      16 distinct banks, 4-lane (e) broadcast -> conflict-free (was 16-way).
//   2. Per-relation bounded pipeline: preload 8 idx (independent ds_reads),
//      issue 8 independent row loads into stA[4]/stB[4] staging (~48 VGPR incl
//      idx; total ~60 < the 64 occupancy cliff), then consume. Serial chain
//      per wave: 3 x (ds + vmem + VALU) instead of 24 x vmem.
//  Gather lane roles (r10/r11-proven): q=l>>4 sub-offset, m=(l>>2)&3 node,
//  e=l&3 16B segment. Reduce over q with PROVEN shfl_xor 16/32.
//  MFMA phase: r11 VERBATIM (self rows direct from feat).
// ---------------------------------------------------------------------------
__global__ __launch_bounds__(256) void k_layer1f(const float* __restrict__ feat,
                                                 const u16* __restrict__ featp,
                                                 const int* __restrict__ adj,
                                                 const f16* __restrict__ Bpack,
                                                 u16* __restrict__ w1, int N) {
    __shared__ f16 x[16][104];       // cols 0..95 used; stride 104 (16B-aligned)
    __shared__ int s_idx[16][100];   // 96 used; stride 100 -> conflict-free reads
    int tid = threadIdx.x;
    int i0 = blockIdx.x * 16;

    {   // stage indices: thread t -> node t>>4, lane16 t&15; 6 coalesced loads
        int node = tid >> 4, l16 = tid & 15;
        int nsafe = (i0 + node < N) ? (i0 + node) : 0;
#pragma unroll
        for (int j = 0; j < 6; ++j) {
            int jj = l16 + j * 16;        // 0..95
            int rr = jj >> 5, kk = jj & 31;
            s_idx[node][jj] = __builtin_nontemporal_load(adj + ((size_t)rr * N + nsafe) * 32 + kk);
        }
    }
    __syncthreads();

    int w = tid >> 6;
    int l = tid & 63;
    int q = l >> 4;        // neighbor sub-offset 0..3
    int m = (l >> 2) & 3;  // node within wave
    int e = l & 3;         // 16B segment of the 64B row
    int nodeLocal = w * 4 + m;
    const u32* fp = (const u32*)featp;   // 16 u32 per 64B row

#pragma unroll
    for (int r = 0; r < 3; ++r) {
        // preload the 8 neighbor indices for this relation (independent ds_reads)
        int idxv[8];
#pragma unroll
        for (int kq = 0; kq < 8; ++kq)
            idxv[kq] = s_idx[nodeLocal][r * 32 + kq * 4 + q];

        // issue all 8 row loads (independent; 2 staging groups of 4)
        u32x4 stA[4], stB[4];
#pragma unroll
        for (int j = 0; j < 4; ++j)
            stA[j] = *(const u32x4*)(fp + (size_t)idxv[j] * 16 + e * 4);
#pragma unroll
        for (int j = 0; j < 4; ++j)
            stB[j] = *(const u32x4*)(fp + (size_t)idxv[4 + j] * 16 + e * 4);

        float acc[8];
#pragma unroll
        for (int j = 0; j < 8; ++j) acc[j] = 0.f;
#pragma unroll
        for (int j = 0; j < 4; ++j) {
            u32x4 v = stA[j];
            acc[0] += bf16_lo(v[0]); acc[1] += bf16_hi(v[0]);
            acc[2] += bf16_lo(v[1]); acc[3] += bf16_hi(v[1]);
            acc[4] += bf16_lo(v[2]); acc[5] += bf16_hi(v[2]);
            acc[6] += bf16_lo(v[3]); acc[7] += bf16_hi(v[3]);
        }
#pragma unroll
        for (int j = 0; j < 4; ++j) {
            u32x4 v = stB[j];
            acc[0] += bf16_lo(v[0]); acc[1] += bf16_hi(v[0]);
            acc[2] += bf16_lo(v[1]); acc[3] += bf16_hi(v[1]);
            acc[4] += bf16_lo(v[2]); acc[5] += bf16_hi(v[2]);
            acc[6] += bf16_lo(v[3]); acc[7] += bf16_hi(v[3]);
        }
#pragma unroll
        for (int j = 0; j < 8; ++j) {   // reduce over q: PROVEN masks 16,32 only
            acc[j] += __shfl_xor(acc[j], 16, 64);
            acc[j] += __shfl_xor(acc[j], 32, 64);
        }
        if (q == 0) {   // 16 lanes write 16B each: cols r*32 + e*8 .. +7
            f16x2 p0, p1, p2, p3;
            p0[0] = (f16)acc[0]; p0[1] = (f16)acc[1];
            p1[0] = (f16)acc[2]; p1[1] = (f16)acc[3];
            p2[0] = (f16)acc[4]; p2[1] = (f16)acc[5];
            p3[0] = (f16)acc[6]; p3[1] = (f16)acc[7];
            u32x4 ov;
            ov[0] = __builtin_bit_cast(u32, p0);
            ov[1] = __builtin_bit_cast(u32, p1);
            ov[2] = __builtin_bit_cast(u32, p2);
            ov[3] = __builtin_bit_cast(u32, p3);
            *(u32x4*)&x[nodeLocal][r * 32 + e * 8] = ov;
        }
    }
    __syncthreads();

    // ---- MFMA phase (r11 VERBATIM; self rows direct from feat) ----
    int nodeA = l & 15;
    int nsA = (i0 + nodeA < N) ? (i0 + nodeA) : 0;
    const float* fr = feat + (size_t)nsA * 25;
#if USE_K16
    f16x4 a[8];
    {
        const f16* xrow = &x[nodeA][(l >> 4) << 2];
#pragma unroll
        for (int ks = 0; ks < 6; ++ks) a[ks] = *(const f16x4*)(xrow + ks * 16);
#pragma unroll
        for (int ks = 6; ks < 8; ++ks)
#pragma unroll
            for (int j = 0; j < 4; ++j) {
                int k = (ks - 6) * 16 + ((l >> 4) << 2) + j;   // self col 0..31
                a[ks][j] = (k < 25) ? (f16)fr[k] : (f16)0.f;
            }
    }
#pragma unroll
    for (int ctt = 0; ctt < 2; ++ctt) {
        int ct = w * 2 + ctt;
        f32x4 d = {0.f, 0.f, 0.f, 0.f};
        const f16* bp = Bpack + ((size_t)(ct * 8) * 64 + l) * 4;
#pragma unroll
        for (int ks = 0; ks < 8; ++ks) {
            f16x4 b = *(const f16x4*)(bp + ks * 256);
            d = __builtin_amdgcn_mfma_f32_16x16x16f16(a[ks], b, d, 0, 0, 0);
        }
#pragma unroll
        for (int reg = 0; reg < 4; ++reg) {
            int n2 = i0 + ((l >> 4) << 2) + reg;
            if (n2 < N) w1[(size_t)n2 * 128 + ct * 16 + (l & 15)] = f2bf(d[reg]);
        }
    }
#else
    f16x8 a[4];
    {
        const f16* xrow = &x[nodeA][(l >> 4) << 3];
#pragma unroll
        for (int ks = 0; ks < 3; ++ks) a[ks] = *(const f16x8*)(xrow + ks * 32);
#pragma unroll
        for (int j = 0; j < 8; ++j) {
            int k = ((l >> 4) << 3) + j;                        // self col 0..31
            a[3][j] = (k < 25) ? (f16)fr[k] : (f16)0.f;
        }
    }
#pragma unroll
    for (int ctt = 0; ctt < 2; ++ctt) {
        int ct = w * 2 + ctt;
        f32x4 d = {0.f, 0.f, 0.f, 0.f};
        const f16* bp = Bpack + ((size_t)(ct * 4) * 64 + l) * 8;
#pragma unroll
        for (int ks = 0; ks < 4; ++ks) {
            f16x8 b = *(const f16x8*)(bp + ks * 512);
            d = __builtin_amdgcn_mfma_f32_16x16x32_f16(a[ks], b, d, 0, 0, 0);
        }
#pragma unroll
        for (int reg = 0; reg < 4; ++reg) {
            int n2 = i0 + ((l >> 4) << 2) + reg;
            if (n2 < N) w1[(size_t)n2 * 128 + ct * 16 + (l & 15)] = f2bf(d[reg]);
        }
    }
#endif
}

// ---------------------------------------------------------------------------
// k_layer2: round-11 VERBATIM (passed).
// ---------------------------------------------------------------------------
__global__ __launch_bounds__(128) void k_layer2(const float* __restrict__ feat,
                                                const float* __restrict__ Wmlp,
                                                const u16* __restrict__ w1h,
                                                const float* __restrict__ alpha2,
                                                const float* __restrict__ lw,
                                                const float* __restrict__ prior,
                                                const int* __restrict__ adj,
                                                const int* __restrict__ nodes,
                                                float* __restrict__ out, int N) {
    __shared__ int s_idx[96];
    __shared__ float s_red[4];
    int b = blockIdx.x;
    int i = nodes[b];
    int t = threadIdx.x;

    if (t < 96) {
        int r = t >> 5, k = t & 31;
        s_idx[t] = adj[((size_t)r * N + i) * 32 + k];
    }
    __syncthreads();

    float mean[3];
#pragma unroll
    for (int r = 0; r < 3; ++r) {
        float acc = 0.f;
#pragma unroll
        for (int k = 0; k < 32; ++k)
            acc += bf16f(w1h[(size_t)s_idx[r * 32 + k] * 128 + t]);  // coalesced
        mean[r] = acc * (1.f / 32.f);
    }

    float et[3], eb[3], st = 0.f, sb = 0.f;
#pragma unroll
    for (int r = 0; r < 3; ++r) {
        et[r] = __expf(alpha2[t * 3 + r]);         st += et[r];
        eb[r] = __expf(alpha2[(128 + t) * 3 + r]); sb += eb[r];
    }
    float t2 = 0.f, wb = 0.f;
#pragma unroll
    for (int r = 0; r < 3; ++r) { t2 += et[r] * mean[r]; wb += eb[r] * mean[r]; }
    t2 /= st;
    wb /= sb;

    float t1 = bf16f(w1h[(size_t)i * 128 + t]);
    float t3 = t1 - wb;

    float p0 = t1 * lw[(64 + t) * 2 + 0] + t2 * lw[(192 + t) * 2 + 0] + t3 * lw[(320 + t) * 2 + 0];
    float p1 = t1 * lw[(64 + t) * 2 + 1] + t2 * lw[(192 + t) * 2 + 1] + t3 * lw[(320 + t) * 2 + 1];
    if (t < 64) {
        float t0 = 0.f;
#pragma unroll
        for (int k = 0; k < 25; ++k) t0 += feat[(size_t)i * 25 + k] * Wmlp[k * 64 + t];
        p0 += t0 * lw[t * 2 + 0];
        p1 += t0 * lw[t * 2 + 1];
    }

#pragma unroll
    for (int off = 32; off > 0; off >>= 1) {
        p0 += __shfl_down(p0, off, 64);
        p1 += __shfl_down(p1, off, 64);
    }
    int wv = t >> 6, lane = t & 63;
    if (lane == 0) { s_red[wv * 2 + 0] = p0; s_red[wv * 2 + 1] = p1; }
    __syncthreads();
    if (t == 0) {
        out[b * 2 + 0] = s_red[0] + s_red[2] + __logf(prior[0]);
        out[b * 2 + 1] = s_red[1] + s_red[3] + __logf(prior[1]);
    }
}

extern "C" void kernel_launch(void* const* d_in, const int* in_sizes, int n_in,
                              void* d_out, int out_size, void* d_ws, size_t ws_size,
                              hipStream_t stream) {
    const float* feat   = (const float*)d_in[0];  // [N,25]
    const float* Wmlp   = (const float*)d_in[1];  // [25,64]
    const float* alpha1 = (const float*)d_in[2];  // [128,3]
    const float* alpha2 = (const float*)d_in[3];  // [256,3]
    const float* lw     = (const float*)d_in[4];  // [448,2]
    const float* prior  = (const float*)d_in[5];  // [2]
    const int*   adj    = (const int*)d_in[6];    // [3,N,32]
    const int*   nodes  = (const int*)d_in[7];    // [B]
    float* out = (float*)d_out;

    int N = in_sizes[0] / 25;   // 50000
    int B = in_sizes[7];        // 1024

    // ws: featp [N][32] u16 (3.2MB) | w1 [N][128] u16 (12.8MB) | Bpack 32KB
    // total ~16.03MB (< 28.8MB proven-safe). NO aliasing.
    char* base = (char*)d_ws;
    u16* featp = (u16*)base;
    u16* w1    = (u16*)(base + (size_t)N * 32 * 2);
    f16* Bpack = (f16*)(base + (size_t)N * 32 * 2 + (size_t)N * 128 * 2);

    k_prep   <<<(N * 32 + 255) / 256, 256, 0, stream>>>(feat, featp, N);
    k_prepM  <<<64,                   256, 0, stream>>>(Wmlp, alpha1, Bpack);
    k_layer1f<<<(N + 15) / 16,        256, 0, stream>>>(feat, featp, adj, Bpack, w1, N);
    k_layer2 <<<B,                    128, 0, stream>>>(feat, Wmlp, w1, alpha2, lw, prior, adj, nodes, out, N);
}